// Round 8
// baseline (156.416 us; speedup 1.0000x reference)
//
#include <hip/hip_runtime.h>

#define NPTS 1000000
#define FDIM 64
#define CNUM 128
#define PSTRIDE 8320          // 8192 sums (c-major [c*64+f]) + 128 counts
#define NB1 1024              // k1 grid: 4 blocks/CU
#define NB3 1024              // k3 grid: 4 blocks/CU

typedef _Float16 half8 __attribute__((ext_vector_type(8)));
typedef float f32x4 __attribute__((ext_vector_type(4)));

// ---------------- K1: cluster sums via MFMA (onehot^T x X), c-split ----------
// One tile stream per block; wave w owns clusters [32w, 32w+32) -> builds one-hot
// for only its 2 ct (no cross-wave duplication) and uses each for 4 MFMAs.
// Tile: M=16 clusters x N=16 feats x K=32 points; acc[2][4] = 32 VGPR.
// A/B layout: lane&15 = m/n; k = (lane>>4)*8 + i. C/D: col=lane&15, row=(lane>>4)*4+reg.
// All 4 waves load the full 8KB feature tile (L1-served redundancy).
__global__ __launch_bounds__(256, 4) void k1_partials(
    const float* __restrict__ feats, const int* __restrict__ labels,
    float* __restrict__ partials, int nblocks)
{
    __shared__ float cnt[CNUM];
    const int tid = threadIdx.x;
    if (tid < CNUM) cnt[tid] = 0.f;
    __syncthreads();

    const int lane = tid & 63;
    const int n15 = lane & 15;
    const int kb = (lane >> 4) * 8;        // k-slot base
    const int rowb = (lane >> 4) * 4;      // C/D row base
    const int w = tid >> 6;                // wave id -> cluster block [32w, 32w+32)

    f32x4 acc[2][4];
    #pragma unroll
    for (int ci = 0; ci < 2; ++ci)
        #pragma unroll
        for (int nt = 0; nt < 4; ++nt)
            acc[ci][nt] = (f32x4){0.f, 0.f, 0.f, 0.f};

    const int ntiles = NPTS / 32;          // 31250
    int t = blockIdx.x;

    // preload tile t
    half8 B[4]; int vl[8]; int cl = 0;
    if (t < ntiles) {
        const int p0 = t * 32;
        const float* fp = feats + (size_t)(p0 + kb) * FDIM + n15;
        const int* lp = labels + 2 * (p0 + kb) + 1;
        #pragma unroll
        for (int nt = 0; nt < 4; ++nt)
            #pragma unroll
            for (int i = 0; i < 8; ++i)
                B[nt][i] = (_Float16)fp[i * FDIM + nt * 16];
        #pragma unroll
        for (int i = 0; i < 8; ++i) vl[i] = lp[2 * i];
        if (w == 0 && lane < 32) cl = labels[2 * (p0 + lane) + 1];
    }
    while (t < ntiles) {
        const int tn = t + nblocks;
        // issue next tile's loads early (T14)
        float fv2[32]; int vl2[8]; int cl2 = 0;
        if (tn < ntiles) {
            const int p0 = tn * 32;
            const float* fp = feats + (size_t)(p0 + kb) * FDIM + n15;
            const int* lp = labels + 2 * (p0 + kb) + 1;
            #pragma unroll
            for (int nt = 0; nt < 4; ++nt)
                #pragma unroll
                for (int i = 0; i < 8; ++i)
                    fv2[nt * 8 + i] = fp[i * FDIM + nt * 16];
            #pragma unroll
            for (int i = 0; i < 8; ++i) vl2[i] = lp[2 * i];
            if (w == 0 && lane < 32) cl2 = labels[2 * (p0 + lane) + 1];
        }
        // counts: wave 0 only
        if (w == 0 && lane < 32) atomicAdd(&cnt[cl], 1.0f);

        // one-hot for my 2 cluster-tiles + 4 MFMAs each
        #pragma unroll
        for (int ci = 0; ci < 2; ++ci) {
            const int cmine = (2 * w + ci) * 16 + n15;
            union { unsigned u[4]; half8 h; } ua;
            #pragma unroll
            for (int j = 0; j < 4; ++j)
                ua.u[j] = ((vl[2 * j] == cmine) ? 0x3C00u : 0u)
                        | ((vl[2 * j + 1] == cmine) ? 0x3C000000u : 0u);
            #pragma unroll
            for (int nt = 0; nt < 4; ++nt)
                acc[ci][nt] = __builtin_amdgcn_mfma_f32_16x16x32_f16(
                    ua.h, B[nt], acc[ci][nt], 0, 0, 0);
        }
        // rotate prefetched tile in
        t = tn;
        #pragma unroll
        for (int nt = 0; nt < 4; ++nt)
            #pragma unroll
            for (int i = 0; i < 8; ++i)
                B[nt][i] = (_Float16)fv2[nt * 8 + i];
        #pragma unroll
        for (int i = 0; i < 8; ++i) vl[i] = vl2[i];
        cl = cl2;
    }
    __syncthreads();

    // direct register -> global writeout, c-major [c*64+f]; waves disjoint in c.
    float* dst = partials + (size_t)blockIdx.x * PSTRIDE;
    #pragma unroll
    for (int ci = 0; ci < 2; ++ci)
        #pragma unroll
        for (int nt = 0; nt < 4; ++nt)
            #pragma unroll
            for (int reg = 0; reg < 4; ++reg) {
                const int c = (2 * w + ci) * 16 + rowb + reg;
                dst[c * FDIM + nt * 16 + n15] = acc[ci][nt][reg];
            }
    if (tid < CNUM) dst[8192 + tid] = cnt[tid];
}

// ---------------- K2: reduce partials -> red (direct write) + zero tails --------
// red[0..8191] c-major [c*64+f]; red[8192..8319] counts. 520 blocks x 16 cols.
__global__ __launch_bounds__(256) void k2_reduce(
    const float* __restrict__ partials, int nblocks, float* __restrict__ red,
    float* __restrict__ ppsum, float* __restrict__ dsum, int* __restrict__ counter)
{
    const int tid = threadIdx.x;
    const int tsub = tid & 15, grp = tid >> 4;      // 16 groups of 16
    const int t0 = blockIdx.x * 16;                 // 520 blocks cover 8320
    float s = 0.f;
    #pragma unroll 8
    for (int b = grp; b < nblocks; b += 16)
        s += partials[(size_t)b * PSTRIDE + t0 + tsub];
    __shared__ float lred[16][17];
    lred[grp][tsub] = s;
    __syncthreads();
    if (tid < 16) {
        float tot = 0.f;
        #pragma unroll
        for (int q = 0; q < 16; ++q) tot += lred[q][tid];
        red[t0 + tid] = tot;                        // already c-major
    }
    if (blockIdx.x == 0) {
        if (tid >= 128) ppsum[tid - 128] = 0.f;
        if (tid == 64) dsum[0] = 0.f;
        if (tid == 65) counter[0] = 0;
    }
}

// ---------------- K3: variance term (prefetch depth 4) ----------------
__global__ __launch_bounds__(256, 4) void k3_var(
    const float4* __restrict__ feats4, const int* __restrict__ labels,
    const float* __restrict__ red, float* __restrict__ ppsum, int nblocks)
{
    __shared__ float4 mu4[CNUM * 16];   // [c][16] (quarter-wave shares c: no pad)
    __shared__ float lpp[CNUM];
    const int tid = threadIdx.x;
    for (int i = tid; i < 2048; i += 256) {
        float4 sv = ((const float4*)red)[i];
        float ci = 1.0f / red[8192 + (i >> 4)];
        mu4[i] = make_float4(sv.x * ci, sv.y * ci, sv.z * ci, sv.w * ci);
    }
    if (tid < CNUM) lpp[tid] = 0.f;
    __syncthreads();

    const int lane = tid & 63;
    const int k = lane & 15, g = lane >> 4;
    const int nwaves = nblocks * 4;
    const int wid = ((blockIdx.x << 8) + tid) >> 6;
    const int ntiles = NPTS / 16;           // 62500 tiles of 16 points

    int b = wid;
    float4 v[4]; int cc = 0;
    if (b < ntiles) {
        const float4* fp = feats4 + (size_t)b * 256 + lane;
        #pragma unroll
        for (int s = 0; s < 4; ++s) v[s] = fp[s * 64];
        cc = labels[2 * (b * 16 + k) + 1];
    }
    while (b < ntiles) {
        const int bn = b + nwaves;
        float4 vn[4]; int ccn = 0;
        if (bn < ntiles) {
            const float4* fp = feats4 + (size_t)bn * 256 + lane;
            #pragma unroll
            for (int s = 0; s < 4; ++s) vn[s] = fp[s * 64];
            ccn = labels[2 * (bn * 16 + k) + 1];
        }
        #pragma unroll
        for (int s = 0; s < 4; ++s) {
            const int c = __shfl(cc, 4 * s + g);
            float4 m = mu4[c * 16 + k];
            float dx = v[s].x - m.x, dy = v[s].y - m.y,
                  dz = v[s].z - m.z, dw = v[s].w - m.w;
            float sq = dx * dx + dy * dy + dz * dz + dw * dw;
            sq += __shfl_xor(sq, 1); sq += __shfl_xor(sq, 2);
            sq += __shfl_xor(sq, 4); sq += __shfl_xor(sq, 8);
            if (k == 0) {
                const float t = sqrtf(sq) - 0.5f;      // DELTA_VAR
                if (t > 0.f) atomicAdd(&lpp[c], t * t);
            }
        }
        b = bn;
        #pragma unroll
        for (int s = 0; s < 4; ++s) v[s] = vn[s];
        cc = ccn;
    }
    __syncthreads();
    if (tid < CNUM) atomicAdd(&ppsum[tid], lpp[tid]);
}

// ---------------- K45: pairwise dist loss + last-block finalize ----------------
__global__ __launch_bounds__(128) void k45_dist_final(
    const float* __restrict__ red, const float* __restrict__ ppsum,
    float* __restrict__ dsum, int* __restrict__ counter, float* __restrict__ out)
{
    __shared__ float4 mu4[CNUM * 17];   // padded: lanes read different rows
    __shared__ int lastflag;
    __shared__ float sv[2];
    const int tid = threadIdx.x;
    for (int i = tid; i < 2048; i += 128) {
        float4 s4 = ((const float4*)red)[i];
        float ci = 1.0f / red[8192 + (i >> 4)];
        mu4[(i >> 4) * 17 + (i & 15)] =
            make_float4(s4.x * ci, s4.y * ci, s4.z * ci, s4.w * ci);
    }
    __syncthreads();
    const int i = blockIdx.x, j = tid;
    float sq = 0.f;
    #pragma unroll
    for (int q = 0; q < 16; ++q) {
        float4 a = mu4[i * 17 + q], b = mu4[j * 17 + q];
        float dx = a.x - b.x, dy = a.y - b.y, dz = a.z - b.z, dw = a.w - b.w;
        sq += dx * dx + dy * dy + dz * dz + dw * dw;
    }
    float dl = 0.f;
    if (j != i) {
        const float r = 3.0f - sqrtf(sq);   // DELTA_DIST
        if (r > 0.f) dl = r * r;
    }
    #pragma unroll
    for (int m = 1; m < 64; m <<= 1) dl += __shfl_xor(dl, m);
    if ((tid & 63) == 0) atomicAdd(dsum, dl);
    __threadfence();
    __syncthreads();
    if (tid == 0) lastflag = (atomicAdd(counter, 1) == (int)gridDim.x - 1);
    __syncthreads();
    if (lastflag) {
        float v = ppsum[tid] / red[8192 + tid];
        #pragma unroll
        for (int m = 1; m < 64; m <<= 1) v += __shfl_xor(v, m);
        if ((tid & 63) == 0) sv[tid >> 6] = v;
    }
    __syncthreads();
    if (lastflag && tid == 0) {
        const float dtot = atomicAdd(dsum, 0.0f);   // device-scope read
        out[0] = (sv[0] + sv[1]) / (float)CNUM
               + dtot / (float)(CNUM * (CNUM - 1));
    }
}

extern "C" void kernel_launch(void* const* d_in, const int* in_sizes, int n_in,
                              void* d_out, int out_size, void* d_ws, size_t ws_size,
                              hipStream_t stream) {
    (void)in_sizes; (void)n_in; (void)out_size;
    const float* feats   = (const float*)d_in[0];
    const float4* feats4 = (const float4*)d_in[0];
    const int* labels    = (const int*)d_in[1];
    float* ws            = (float*)d_ws;
    float* out           = (float*)d_out;

    int nb1 = NB1;
    {
        size_t avail = ws_size / sizeof(float);
        size_t fixed = PSTRIDE + 128 + 2;           // red + ppsum + dsum + counter
        if (avail > fixed) {
            size_t cap = (avail - fixed) / PSTRIDE;
            if ((size_t)nb1 > cap) nb1 = (int)cap;
        } else nb1 = 1;
        if (nb1 < 1) nb1 = 1;
    }
    float* partials = ws;
    float* red      = ws + (size_t)nb1 * PSTRIDE;   // 16B-aligned
    float* ppsum    = red + PSTRIDE;
    float* dsum     = ppsum + 128;
    int*   counter  = (int*)(dsum + 1);

    k1_partials<<<nb1, 256, 0, stream>>>(feats, labels, partials, nb1);
    k2_reduce<<<PSTRIDE / 16, 256, 0, stream>>>(partials, nb1, red, ppsum, dsum, counter);
    k3_var<<<NB3, 256, 0, stream>>>(feats4, labels, red, ppsum, NB3);
    k45_dist_final<<<CNUM, 128, 0, stream>>>(red, ppsum, dsum, counter, out);
}

// Round 10
// 131.044 us; speedup vs baseline: 1.1936x; 1.1936x over previous
//
#include <hip/hip_runtime.h>

#define NPTS 1000000
#define FDIM 64
#define CNUM 128
#define PSTRIDE 8320          // 8192 sums (f-major [f*128+c]) + 128 counts
#define NB1 1024              // k1 grid: 4 blocks/CU
#define NB3 1024              // k3 grid: 4 blocks/CU

typedef _Float16 half8 __attribute__((ext_vector_type(8)));
typedef float f32x4 __attribute__((ext_vector_type(4)));

// ---------------- K1: cluster sums via MFMA (onehot^T x X), f-half split ----------
// Round-6 proven structure: wave-pair (2w,2w+1) shares a tile stream; wave handles
// f in [fh*32, fh*32+32). acc[8][2] = 64 VGPR -> 16 waves/CU.
// Partials written with NONTEMPORAL stores: no L3 allocation, so the 244MB feature
// array stays L3-resident for k3 (which reads it in reverse).
__global__ __launch_bounds__(256, 4) void k1_partials(
    const float* __restrict__ feats, const int* __restrict__ labels,
    float* __restrict__ partials, int nblocks)
{
    __shared__ float lds[FDIM * 132];      // [f][c] padded to 132
    __shared__ float cnt[CNUM];
    const int tid = threadIdx.x;
    if (tid < CNUM) cnt[tid] = 0.f;
    __syncthreads();

    const int lane = tid & 63;
    const int n15 = lane & 15;
    const int kb = (lane >> 4) * 8;        // k-slot base
    const int rowb = (lane >> 4) * 4;      // C/D row base
    const int w = tid >> 6;
    const int fh = w & 1;                  // feature half
    const int fbase = fh * 32;
    const int nstreams = nblocks * 2;
    const int ts = ((blockIdx.x << 2) + w) >> 1;   // tile stream id

    f32x4 acc[8][2];
    #pragma unroll
    for (int ct = 0; ct < 8; ++ct)
        #pragma unroll
        for (int nt = 0; nt < 2; ++nt)
            acc[ct][nt] = (f32x4){0.f, 0.f, 0.f, 0.f};

    const int ntiles = NPTS / 32;          // 31250
    for (int t = ts; t < ntiles; t += nstreams) {
        const int p0 = t * 32;
        const float* fp = feats + (size_t)(p0 + kb) * FDIM + fbase + n15;
        const int* lp = labels + 2 * (p0 + kb) + 1;
        int vlab[8];
        #pragma unroll
        for (int i = 0; i < 8; ++i) vlab[i] = lp[2 * i];

        half8 B[2];
        #pragma unroll
        for (int nt = 0; nt < 2; ++nt) {
            #pragma unroll
            for (int i = 0; i < 8; ++i)
                B[nt][i] = (_Float16)fp[i * FDIM + nt * 16];
        }
        // counts: fh==0 waves only, one lane-op per point
        if (fh == 0 && lane < 32) {
            const int myl = labels[2 * (p0 + lane) + 1];
            atomicAdd(&cnt[myl], 1.0f);
        }
        #pragma unroll
        for (int ct = 0; ct < 8; ++ct) {
            const int cmine = ct * 16 + n15;
            union { unsigned u[4]; half8 h; } ua;
            #pragma unroll
            for (int j = 0; j < 4; ++j)
                ua.u[j] = ((vlab[2 * j] == cmine) ? 0x3C00u : 0u)
                        | ((vlab[2 * j + 1] == cmine) ? 0x3C000000u : 0u);
            #pragma unroll
            for (int nt = 0; nt < 2; ++nt)
                acc[ct][nt] = __builtin_amdgcn_mfma_f32_16x16x32_f16(
                    ua.h, B[nt], acc[ct][nt], 0, 0, 0);
        }
    }
    __syncthreads();

    // 2-round merge: waves 0,1 write (disjoint f-halves); waves 2,3 add.
    for (int r = 0; r < 2; ++r) {
        if ((w >> 1) == r) {
            #pragma unroll
            for (int ct = 0; ct < 8; ++ct)
                #pragma unroll
                for (int nt = 0; nt < 2; ++nt) {
                    float* a = &lds[(fbase + nt * 16 + n15) * 132 + ct * 16 + rowb];
                    if (r == 0) *(f32x4*)a = acc[ct][nt];
                    else        *(f32x4*)a = *(f32x4*)a + acc[ct][nt];
                }
        }
        __syncthreads();
    }

    // nontemporal writeout: bypass L3 allocation (preserve feature residency)
    float* dst = partials + (size_t)blockIdx.x * PSTRIDE;
    for (int i4 = tid; i4 < 2048; i4 += 256) {        // float4 units, f-major
        const int f = i4 >> 5, c0 = (i4 & 31) * 4;
        __builtin_nontemporal_store(*(const f32x4*)&lds[f * 132 + c0],
                                    (f32x4*)dst + i4);
    }
    if (tid < CNUM)
        __builtin_nontemporal_store(cnt[tid], &dst[8192 + tid]);
}

// ---------------- K2: reduce partials -> red (nontemporal reads) ----------------
// red[0..8191] c-major [c*64+f]; red[8192..8319] counts.
__global__ __launch_bounds__(256) void k2_reduce(
    const float* __restrict__ partials, int nblocks, float* __restrict__ red,
    float* __restrict__ ppsum, float* __restrict__ dsum, int* __restrict__ counter)
{
    const int tid = threadIdx.x;
    const int tsub = tid & 31, grp = tid >> 5;
    const int t0 = blockIdx.x * 32;                 // 260 blocks cover 8320
    float s = 0.f;
    #pragma unroll 8
    for (int b = grp; b < nblocks; b += 8)
        s += __builtin_nontemporal_load(&partials[(size_t)b * PSTRIDE + t0 + tsub]);
    __shared__ float lred[8][33];
    lred[grp][tsub] = s;
    __syncthreads();
    if (tid < 32) {
        float tot = 0.f;
        #pragma unroll
        for (int q = 0; q < 8; ++q) tot += lred[q][tid];
        const int t = t0 + tid;
        if (t < 8192) red[(t & 127) * FDIM + (t >> 7)] = tot;  // f-major -> c-major
        else red[t] = tot;
    }
    if (blockIdx.x == 0) {
        if (tid >= 128) ppsum[tid - 128] = 0.f;
        if (tid == 64) dsum[0] = 0.f;
        if (tid == 65) counter[0] = 0;
    }
}

// ---------------- K3: variance term (REVERSE traversal for L3 reuse) -------------
__global__ __launch_bounds__(256, 4) void k3_var(
    const float4* __restrict__ feats4, const int* __restrict__ labels,
    const float* __restrict__ red, float* __restrict__ ppsum, int nblocks)
{
    __shared__ float4 mu4[CNUM * 16];   // [c][16] (quarter-wave shares c: no pad)
    __shared__ float lpp[CNUM];
    const int tid = threadIdx.x;
    for (int i = tid; i < 2048; i += 256) {
        float4 sv = ((const float4*)red)[i];
        float ci = 1.0f / red[8192 + (i >> 4)];
        mu4[i] = make_float4(sv.x * ci, sv.y * ci, sv.z * ci, sv.w * ci);
    }
    if (tid < CNUM) lpp[tid] = 0.f;
    __syncthreads();

    const int lane = tid & 63;
    const int k = lane & 15, g = lane >> 4;
    const int nwaves = nblocks * 4;
    const int wid = ((blockIdx.x << 8) + tid) >> 6;
    const int ntiles = NPTS / 16;           // 62500 tiles of 16 points

    // reverse: start at the tail (most recently L3-cached by k1), walk backward
    int b = ntiles - 1 - wid;
    float4 v[4]; int cc = 0;
    if (b >= 0) {
        const float4* fp = feats4 + (size_t)b * 256 + lane;
        #pragma unroll
        for (int s = 0; s < 4; ++s) v[s] = fp[s * 64];
        cc = labels[2 * (b * 16 + k) + 1];
    }
    while (b >= 0) {
        const int bn = b - nwaves;
        float4 vn[4]; int ccn = 0;
        if (bn >= 0) {
            const float4* fp = feats4 + (size_t)bn * 256 + lane;
            #pragma unroll
            for (int s = 0; s < 4; ++s) vn[s] = fp[s * 64];
            ccn = labels[2 * (bn * 16 + k) + 1];
        }
        #pragma unroll
        for (int s = 0; s < 4; ++s) {
            const int c = __shfl(cc, 4 * s + g);
            float4 m = mu4[c * 16 + k];
            float dx = v[s].x - m.x, dy = v[s].y - m.y,
                  dz = v[s].z - m.z, dw = v[s].w - m.w;
            float sq = dx * dx + dy * dy + dz * dz + dw * dw;
            sq += __shfl_xor(sq, 1); sq += __shfl_xor(sq, 2);
            sq += __shfl_xor(sq, 4); sq += __shfl_xor(sq, 8);
            if (k == 0) {
                const float t = sqrtf(sq) - 0.5f;      // DELTA_VAR
                if (t > 0.f) atomicAdd(&lpp[c], t * t);
            }
        }
        b = bn;
        #pragma unroll
        for (int s = 0; s < 4; ++s) v[s] = vn[s];
        cc = ccn;
    }
    __syncthreads();
    if (tid < CNUM) atomicAdd(&ppsum[tid], lpp[tid]);
}

// ---------------- K45: pairwise dist loss + last-block finalize ----------------
__global__ __launch_bounds__(128) void k45_dist_final(
    const float* __restrict__ red, const float* __restrict__ ppsum,
    float* __restrict__ dsum, int* __restrict__ counter, float* __restrict__ out)
{
    __shared__ float4 mu4[CNUM * 17];   // padded: lanes read different rows
    __shared__ int lastflag;
    __shared__ float sv[2];
    const int tid = threadIdx.x;
    for (int i = tid; i < 2048; i += 128) {
        float4 s4 = ((const float4*)red)[i];
        float ci = 1.0f / red[8192 + (i >> 4)];
        mu4[(i >> 4) * 17 + (i & 15)] =
            make_float4(s4.x * ci, s4.y * ci, s4.z * ci, s4.w * ci);
    }
    __syncthreads();
    const int i = blockIdx.x, j = tid;
    float sq = 0.f;
    #pragma unroll
    for (int q = 0; q < 16; ++q) {
        float4 a = mu4[i * 17 + q], b = mu4[j * 17 + q];
        float dx = a.x - b.x, dy = a.y - b.y, dz = a.z - b.z, dw = a.w - b.w;
        sq += dx * dx + dy * dy + dz * dz + dw * dw;
    }
    float dl = 0.f;
    if (j != i) {
        const float r = 3.0f - sqrtf(sq);   // DELTA_DIST
        if (r > 0.f) dl = r * r;
    }
    #pragma unroll
    for (int m = 1; m < 64; m <<= 1) dl += __shfl_xor(dl, m);
    if ((tid & 63) == 0) atomicAdd(dsum, dl);
    __threadfence();
    __syncthreads();
    if (tid == 0) lastflag = (atomicAdd(counter, 1) == (int)gridDim.x - 1);
    __syncthreads();
    if (lastflag) {
        float v = ppsum[tid] / red[8192 + tid];
        #pragma unroll
        for (int m = 1; m < 64; m <<= 1) v += __shfl_xor(v, m);
        if ((tid & 63) == 0) sv[tid >> 6] = v;
    }
    __syncthreads();
    if (lastflag && tid == 0) {
        const float dtot = atomicAdd(dsum, 0.0f);   // device-scope read
        out[0] = (sv[0] + sv[1]) / (float)CNUM
               + dtot / (float)(CNUM * (CNUM - 1));
    }
}

extern "C" void kernel_launch(void* const* d_in, const int* in_sizes, int n_in,
                              void* d_out, int out_size, void* d_ws, size_t ws_size,
                              hipStream_t stream) {
    (void)in_sizes; (void)n_in; (void)out_size;
    const float* feats   = (const float*)d_in[0];
    const float4* feats4 = (const float4*)d_in[0];
    const int* labels    = (const int*)d_in[1];
    float* ws            = (float*)d_ws;
    float* out           = (float*)d_out;

    int nb1 = NB1;
    {
        size_t avail = ws_size / sizeof(float);
        size_t fixed = PSTRIDE + 128 + 2;           // red + ppsum + dsum + counter
        if (avail > fixed) {
            size_t cap = (avail - fixed) / PSTRIDE;
            if ((size_t)nb1 > cap) nb1 = (int)cap;
        } else nb1 = 1;
        if (nb1 < 1) nb1 = 1;
    }
    float* partials = ws;
    float* red      = ws + (size_t)nb1 * PSTRIDE;   // 16B-aligned
    float* ppsum    = red + PSTRIDE;
    float* dsum     = ppsum + 128;
    int*   counter  = (int*)(dsum + 1);

    k1_partials<<<nb1, 256, 0, stream>>>(feats, labels, partials, nb1);
    k2_reduce<<<PSTRIDE / 32, 256, 0, stream>>>(partials, nb1, red, ppsum, dsum, counter);
    k3_var<<<NB3, 256, 0, stream>>>(feats4, labels, red, ppsum, NB3);
    k45_dist_final<<<CNUM, 128, 0, stream>>>(red, ppsum, dsum, counter, out);
}